// Round 1
// 139.492 us; speedup vs baseline: 1.0819x; 1.0819x over previous
//
#include <hip/hip_runtime.h>
#include <math.h>

#define NB 2
#define NO 512
#define NQ 512
#define OUT_DIM 128
#define LPAD 514   // logits row pitch (floats)

typedef __attribute__((ext_vector_type(8))) short short8;     // 8 bf16
typedef __attribute__((ext_vector_type(8))) _Float16 half8;   // 8 f16 (4 VGPR)
typedef __attribute__((ext_vector_type(4))) float f32x4;      // MFMA acc
typedef float v2f __attribute__((ext_vector_type(2)));

__device__ __forceinline__ float softplus_f(float x) {
  return x > 0.0f ? x + log1pf(expf(-x)) : log1pf(expf(x));
}
__device__ __forceinline__ unsigned short bf16_rne(float f) {
  unsigned u = __float_as_uint(f);
  unsigned r = u + 0x7FFFu + ((u >> 16) & 1u);
  return (unsigned short)(r >> 16);
}
// unpack u32 (2 bf16) -> v2f {low, high}
__device__ __forceinline__ v2f unpk_bf2(unsigned u) {
  v2f r; r.x = __uint_as_float(u << 16); r.y = __uint_as_float(u & 0xFFFF0000u);
  return r;
}
__device__ __forceinline__ v2f splat2(float x) { v2f r; r.x = x; r.y = x; return r; }
__device__ __forceinline__ v2f fma2(v2f a, v2f b, v2f c) { return __builtin_elementwise_fma(a, b, c); }
__device__ __forceinline__ v2f max2(v2f a, v2f b) { return __builtin_elementwise_max(a, b); }
// 2 f32 -> packed 2 f16 (RTZ) in one instruction
__device__ __forceinline__ int cvt2h(float x, float y) {
  return __builtin_bit_cast(int, __builtin_amdgcn_cvt_pkrtz(x, y));
}
// butterfly allreduce over lane bits 3..5 (the 8 o-slices)
__device__ __forceinline__ v2f bfly_s(v2f x) {
  #pragma unroll
  for (int off = 8; off <= 32; off <<= 1) {
    x.x += __shfl_xor(x.x, off, 64);
    x.y += __shfl_xor(x.y, off, 64);
  }
  return x;
}

// ---------------------------------------------------------------------------
// Prep: blocks 0..255 fused 2-layer MLP -> V (bf16); 256..511 AO (bf16).
// (unchanged from previous version)
__global__ __launch_bounds__(1024) void prep_kernel(
    const float* __restrict__ h_obs, const float* __restrict__ fw1,
    const float* __restrict__ fb1, const float* __restrict__ fw2,
    const float* __restrict__ fb2, const float* __restrict__ pos_obs,
    const float* __restrict__ kw1, unsigned short* __restrict__ V_bf,
    unsigned short* __restrict__ AO_bf)
{
  if (blockIdx.x < 256) {
    __shared__ float s_red[4][4][256];
    __shared__ float s_hid[4][256];
    const int n  = threadIdx.x & 255;
    const int ks = threadIdx.x >> 8;
    const int r0 = blockIdx.x * 4;
    const int k0 = ks * 64;
    float a0 = 0.f, a1 = 0.f, a2 = 0.f, a3 = 0.f;
    #pragma unroll 8
    for (int kk = 0; kk < 64; ++kk) {
      int k = k0 + kk;
      float w = fw1[k * 256 + n];
      a0 = fmaf(h_obs[(r0 + 0) * 256 + k], w, a0);
      a1 = fmaf(h_obs[(r0 + 1) * 256 + k], w, a1);
      a2 = fmaf(h_obs[(r0 + 2) * 256 + k], w, a2);
      a3 = fmaf(h_obs[(r0 + 3) * 256 + k], w, a3);
    }
    s_red[ks][0][n] = a0; s_red[ks][1][n] = a1;
    s_red[ks][2][n] = a2; s_red[ks][3][n] = a3;
    __syncthreads();
    if (ks == 0) {
      float bb = fb1[n];
      #pragma unroll
      for (int r = 0; r < 4; ++r) {
        float v = s_red[0][r][n] + s_red[1][r][n] + s_red[2][r][n] + s_red[3][r][n] + bb;
        s_hid[r][n] = fmaxf(v, 0.f);
      }
    }
    __syncthreads();
    float c0 = 0.f, c1 = 0.f, c2 = 0.f, c3 = 0.f;
    #pragma unroll 8
    for (int kk = 0; kk < 64; ++kk) {
      int k = k0 + kk;
      float w = fw2[k * 256 + n];
      c0 = fmaf(s_hid[0][k], w, c0);
      c1 = fmaf(s_hid[1][k], w, c1);
      c2 = fmaf(s_hid[2][k], w, c2);
      c3 = fmaf(s_hid[3][k], w, c3);
    }
    __syncthreads();
    s_red[ks][0][n] = c0; s_red[ks][1][n] = c1;
    s_red[ks][2][n] = c2; s_red[ks][3][n] = c3;
    __syncthreads();
    if (ks == 0) {
      float bb = fb2[n];
      #pragma unroll
      for (int r = 0; r < 4; ++r) {
        float v = s_red[0][r][n] + s_red[1][r][n] + s_red[2][r][n] + s_red[3][r][n] + bb;
        V_bf[(size_t)(r0 + r) * 256 + n] = bf16_rne(v);
      }
    }
  } else {
    const int i  = blockIdx.x - 256;
    const int b  = i >> 7;
    const int og = i & 127;
    const int ol = threadIdx.x >> 8;
    const int j  = threadIdx.x & 255;
    const int o  = og * 4 + ol;
    float c0 = kw1[3 * 256 + j] - kw1[6 * 256 + j];
    float c1 = kw1[4 * 256 + j] - kw1[7 * 256 + j];
    float c2 = kw1[5 * 256 + j] - kw1[8 * 256 + j];
    const float* p = pos_obs + ((size_t)(b * NO + o)) * 3;
    AO_bf[(size_t)(b * NO + o) * 256 + j] =
        bf16_rne(fmaf(p[0], c0, fmaf(p[1], c1, p[2] * c2)));
  }
}

// ---------------------------------------------------------------------------
// Fused attention + out_proj. QT=2 per block, 512 threads (8 waves).
// Phase 1: single f16 MFMA 16x16x32 (A = relu(aq+ao) via v_cvt_pkrtz, B = kw2
//          single f16 — more accurate on A than bf16 + no hi/lo double-MFMA).
// Phase 3: wave=head mapping; cross-slice reduction via shfl_xor butterfly
//          (no 18KB LDS staging, no extra barriers).
__global__ __launch_bounds__(512, 4) void attn_fused(
    const unsigned short* __restrict__ V_bf,   // (B*NO, 256) bf16
    const unsigned short* __restrict__ AO_bf,  // (B*NO, 256) bf16
    const float* __restrict__ kw1,       // (9, 256)
    const float* __restrict__ kb1,       // (256)
    const float* __restrict__ kw2,       // (256, 8)
    const float* __restrict__ kb2,       // (8)
    const float* __restrict__ log_sigma, // (8)
    const float* __restrict__ pos_obs,   // (B*NO, 3)
    const float* __restrict__ pos_query, // (B*NQ, 3)
    const float* __restrict__ ow, const float* __restrict__ obias,
    const float* __restrict__ vw, const float* __restrict__ vbias,
    float* __restrict__ out)
{
  __shared__ float s_logits[2][8 * LPAD];        // 32896 B
  __shared__ half8 s_Bh[512];                    // 8192 B  (kw2 f16 fragments)
  __shared__ __align__(16) float s_pool[2048];   // 8192 B
  __shared__ float s_sum[2][8];

  float* s_aq   = s_pool;          // [q*256 + j]        (phase 1)
  float* s_hv   = s_pool;          // [(q*2+kind)*256+hd] (phase 3/4)
  float* s_pred = s_pool + 1024;   // [ks][mode][q][128]  (phase 4)

  const int t   = threadIdx.x;
  const int bq0 = blockIdx.x * 2;
  const int b   = bq0 >> 9;

  // ---- prologue -----------------------------------------------------------
  float pqx[2], pqy[2], pqz[2];
  #pragma unroll
  for (int q = 0; q < 2; ++q) {
    pqx[q] = pos_query[(bq0 + q) * 3 + 0];
    pqy[q] = pos_query[(bq0 + q) * 3 + 1];
    pqz[q] = pos_query[(bq0 + q) * 3 + 2];
  }
  // aq[q][j]
  {
    const int q = t >> 8, j = t & 255;
    float c0 = kw1[0 * 256 + j] + kw1[6 * 256 + j];
    float c1 = kw1[1 * 256 + j] + kw1[7 * 256 + j];
    float c2 = kw1[2 * 256 + j] + kw1[8 * 256 + j];
    s_aq[q * 256 + j] =
        fmaf(pqx[q], c0, fmaf(pqy[q], c1, fmaf(pqz[q], c2, kb1[j])));
  }
  // logits prefill: rbf + kb2 for o = t, both q, all h (fast exp/log)
  {
    const int o = t;
    const float* p = pos_obs + (size_t)(b * NO + o) * 3;
    float px = p[0], py = p[1], pz = p[2];
    float d2q[2];
    #pragma unroll
    for (int q = 0; q < 2; ++q) {
      float r0 = pqx[q] - px, r1 = pqy[q] - py, r2 = pqz[q] - pz;
      d2q[q] = r0 * r0 + r1 * r1 + r2 * r2;
    }
    #pragma unroll
    for (int h = 0; h < 8; ++h) {
      float sg  = __expf(log_sigma[h]);
      float inv = 1.0f / (sg * sg + 1e-6f);
      float kbv = kb2[h];
      s_logits[0][h * LPAD + o] = __logf(__expf(-d2q[0] * inv) + 1e-8f) + kbv;
      s_logits[1][h * LPAD + o] = __logf(__expf(-d2q[1] * inv) + 1e-8f) + kbv;
    }
  }
  // B fragments: kw2 as single f16 (RNE cast)
  {
    const int kstep = t >> 6, lane = t & 63;
    const int nh = lane & 15;
    const int kb_ = kstep * 32 + ((lane >> 4) & 3) * 8;
    half8 b8;
    #pragma unroll
    for (int i = 0; i < 8; ++i) {
      float v = (nh < 8) ? kw2[(kb_ + i) * 8 + nh] : 0.f;
      b8[i] = (_Float16)v;
    }
    s_Bh[kstep * 64 + lane] = b8;
  }
  __syncthreads();

  // ---- phase 1: f16 MFMA delta, accumulate into prefilled logits ----------
  {
    const int wave = t >> 6, lane = t & 63;
    const int quad = lane >> 4, mrow = lane & 15;
    const int tb   = wave * 4;                   // 4 o-tiles per wave, both q
    f32x4 C[2][4];
    #pragma unroll
    for (int q = 0; q < 2; ++q)
      #pragma unroll
      for (int jt = 0; jt < 4; ++jt) C[q][jt] = (f32x4){0.f, 0.f, 0.f, 0.f};

    for (int kstep = 0; kstep < 8; ++kstep) {
      const int koff = kstep * 32 + quad * 8;
      const v2f* aqp0 = (const v2f*)(s_aq + koff);
      const v2f* aqp1 = (const v2f*)(s_aq + 256 + koff);
      v2f aq0[4], aq1[4];
      #pragma unroll
      for (int i = 0; i < 4; ++i) { aq0[i] = aqp0[i]; aq1[i] = aqp1[i]; }
      half8 bh = s_Bh[kstep * 64 + lane];
      #pragma unroll
      for (int jt = 0; jt < 4; ++jt) {
        const int o = (tb + jt) * 16 + mrow;
        int4 u = *(const int4*)(AO_bf + ((b * NO + o) << 8) + koff);
        v2f ao0 = unpk_bf2((unsigned)u.x), ao1 = unpk_bf2((unsigned)u.y);
        v2f ao2 = unpk_bf2((unsigned)u.z), ao3 = unpk_bf2((unsigned)u.w);
        v2f z = splat2(0.f);
        int4 af0, af1;
        {
          v2f h0 = max2(aq0[0] + ao0, z), h1 = max2(aq0[1] + ao1, z);
          v2f h2 = max2(aq0[2] + ao2, z), h3 = max2(aq0[3] + ao3, z);
          af0.x = cvt2h(h0.x, h0.y); af0.y = cvt2h(h1.x, h1.y);
          af0.z = cvt2h(h2.x, h2.y); af0.w = cvt2h(h3.x, h3.y);
        }
        {
          v2f h0 = max2(aq1[0] + ao0, z), h1 = max2(aq1[1] + ao1, z);
          v2f h2 = max2(aq1[2] + ao2, z), h3 = max2(aq1[3] + ao3, z);
          af1.x = cvt2h(h0.x, h0.y); af1.y = cvt2h(h1.x, h1.y);
          af1.z = cvt2h(h2.x, h2.y); af1.w = cvt2h(h3.x, h3.y);
        }
        half8 a0 = __builtin_bit_cast(half8, af0);
        half8 a1 = __builtin_bit_cast(half8, af1);
        C[0][jt] = __builtin_amdgcn_mfma_f32_16x16x32_f16(a0, bh, C[0][jt], 0, 0, 0);
        C[1][jt] = __builtin_amdgcn_mfma_f32_16x16x32_f16(a1, bh, C[1][jt], 0, 0, 0);
      }
    }
    // epilogue: D[n=h=lane&15][m=quad*4+r]; add delta into prefilled logits
    const int hh = lane & 15;
    if (hh < 8) {
      #pragma unroll
      for (int q = 0; q < 2; ++q)
        #pragma unroll
        for (int jt = 0; jt < 4; ++jt) {
          const int ob2 = (tb + jt) * 16 + quad * 4;
          #pragma unroll
          for (int r = 0; r < 4; ++r)
            s_logits[q][hh * LPAD + ob2 + r] += C[q][jt][r];
        }
    }
  }
  __syncthreads();

  // ---- phase 2: softmax (8 waves x 2 (q,h) rows) --------------------------
  {
    const int wave = t >> 6, lane = t & 63;
    #pragma unroll
    for (int cc = 0; cc < 2; ++cc) {
      const int c = wave * 2 + cc;
      const int q = c >> 3, h = c & 7;
      float* pl = &s_logits[q][h * LPAD];
      float l[8];
      float m = -1e30f;
      #pragma unroll
      for (int k = 0; k < 8; ++k) {
        l[k] = pl[k * 64 + lane];
        m = fmaxf(m, l[k]);
      }
      #pragma unroll
      for (int off = 32; off >= 1; off >>= 1) m = fmaxf(m, __shfl_xor(m, off, 64));
      float s = 0.f;
      #pragma unroll
      for (int k = 0; k < 8; ++k) {
        float p = __expf(l[k] - m);
        pl[k * 64 + lane] = p;
        s += p;
      }
      #pragma unroll
      for (int off = 32; off >= 1; off >>= 1) s += __shfl_xor(s, off, 64);
      if (lane == 0) s_sum[q][h] = s;
    }
  }
  __syncthreads();

  // ---- phase 3: PV + P V^2; wave = head, lane = (slice s5, d-group dg) ----
  // Cross-slice reduction in-register via shfl_xor butterfly (no LDS staging).
  {
    const int h  = t >> 6;          // wave = head
    const int l  = t & 63;
    const int s5 = l >> 3;          // o-slice (64 o each)
    const int dg = l & 7;           // d-group (4 d each)
    const unsigned short* vb_ = V_bf + ((b * NO) << 8) + h * 32 + dg * 4;
    const float* P0 = &s_logits[0][h * LPAD];
    const float* P1 = &s_logits[1][h * LPAD];
    v2f A0 = splat2(0.f), B0 = A0, C0 = A0, D0 = A0;   // q0: S1(d01),S1(d23),S2(d01),S2(d23)
    v2f A1 = A0, B1 = A0, C1 = A0, D1 = A0;            // q1
    const int ob = s5 * 64, rot = s5 * 8;
    #pragma unroll 4
    for (int oi = 0; oi < 64; oi += 2) {
      const int oo = ob + ((oi + rot) & 63);           // even; rotation keeps
      v2f p0 = *(const v2f*)(P0 + oo);                 //  LDS banks spread
      v2f p1 = *(const v2f*)(P1 + oo);
      uint2 v0 = *(const uint2*)(vb_ + (oo << 8));
      uint2 v1 = *(const uint2*)(vb_ + ((oo + 1) << 8));
      v2f va0 = unpk_bf2(v0.x), vb0 = unpk_bf2(v0.y);
      v2f va1 = unpk_bf2(v1.x), vb1 = unpk_bf2(v1.y);
      v2f t0, t1;
      // o (even)
      v2f p00 = splat2(p0.x), p10 = splat2(p1.x);
      A0 = fma2(p00, va0, A0); B0 = fma2(p00, vb0, B0);
      t0 = p00 * va0; C0 = fma2(t0, va0, C0);
      t1 = p00 * vb0; D0 = fma2(t1, vb0, D0);
      A1 = fma2(p10, va0, A1); B1 = fma2(p10, vb0, B1);
      t0 = p10 * va0; C1 = fma2(t0, va0, C1);
      t1 = p10 * vb0; D1 = fma2(t1, vb0, D1);
      // o+1 (odd)
      v2f p01 = splat2(p0.y), p11 = splat2(p1.y);
      A0 = fma2(p01, va1, A0); B0 = fma2(p01, vb1, B0);
      t0 = p01 * va1; C0 = fma2(t0, va1, C0);
      t1 = p01 * vb1; D0 = fma2(t1, vb1, D0);
      A1 = fma2(p11, va1, A1); B1 = fma2(p11, vb1, B1);
      t0 = p11 * va1; C1 = fma2(t0, va1, C1);
      t1 = p11 * vb1; D1 = fma2(t1, vb1, D1);
    }
    // allreduce over the 8 slices (lane bits 3..5)
    A0 = bfly_s(A0); B0 = bfly_s(B0); C0 = bfly_s(C0); D0 = bfly_s(D0);
    A1 = bfly_s(A1); B1 = bfly_s(B1); C1 = bfly_s(C1); D1 = bfly_s(D1);
    // 4 writer slices: s5 = (q<<1)|kind; every lane has the full sums
    if (s5 < 4) {
      const int q = s5 >> 1, kind = s5 & 1;
      v2f S1a = q ? A1 : A0, S1b = q ? B1 : B0;
      v2f S2a = q ? C1 : C0, S2b = q ? D1 : D0;
      float inv = 1.0f / s_sum[q][h];
      float m0 = S1a.x * inv, m1 = S1a.y * inv;
      float m2 = S1b.x * inv, m3 = S1b.y * inv;
      float4 w;
      if (kind == 0) {
        w = (float4){m0, m1, m2, m3};
      } else {
        w = (float4){fmaxf(S2a.x * inv - m0 * m0, 0.f),
                     fmaxf(S2a.y * inv - m1 * m1, 0.f),
                     fmaxf(S2b.x * inv - m2 * m2, 0.f),
                     fmaxf(S2b.y * inv - m3 * m3, 0.f)};
      }
      *(float4*)(s_hv + (q * 2 + kind) * 256 + h * 32 + dg * 4) = w;
    }
  }
  __syncthreads();

  // ---- phase 4: out_proj, k-split 2, W read once per (mode,ks) ------------
  {
    const int ks = t >> 8, mode = (t >> 7) & 1, n = t & 127;
    const float* W  = mode ? vw : ow;
    const float* X0 = s_hv + mode * 256;        // q0
    const float* X1 = s_hv + (2 + mode) * 256;  // q1
    float a0 = 0.f, a1 = 0.f;
    const int k0 = ks * 128;
    #pragma unroll 4
    for (int k = k0; k < k0 + 128; k += 4) {
      float4 x0 = *(const float4*)&X0[k];
      float4 x1 = *(const float4*)&X1[k];
      float w0 = W[(k + 0) * 128 + n];
      float w1 = W[(k + 1) * 128 + n];
      float w2 = W[(k + 2) * 128 + n];
      float w3 = W[(k + 3) * 128 + n];
      a0 = fmaf(x0.x, w0, a0); a1 = fmaf(x1.x, w0, a1);
      a0 = fmaf(x0.y, w1, a0); a1 = fmaf(x1.y, w1, a1);
      a0 = fmaf(x0.z, w2, a0); a1 = fmaf(x1.z, w2, a1);
      a0 = fmaf(x0.w, w3, a0); a1 = fmaf(x1.w, w3, a1);
    }
    s_pred[((ks * 2 + mode) * 2 + 0) * 128 + n] = a0;   // s_pred disjoint from s_hv
    s_pred[((ks * 2 + mode) * 2 + 1) * 128 + n] = a1;
  }
  __syncthreads();
  {
    const int q = t >> 8, mode = (t >> 7) & 1, n = t & 127;
    float v = s_pred[((0 * 2 + mode) * 2 + q) * 128 + n]
            + s_pred[((1 * 2 + mode) * 2 + q) * 128 + n]
            + (mode ? vbias[n] : obias[n]);
    if (mode) v = softplus_f(v);
    out[(size_t)mode * (NB * NQ * OUT_DIM) + (size_t)(bq0 + q) * OUT_DIM + n] = v;
  }
}

// ---------------------------------------------------------------------------
extern "C" void kernel_launch(void* const* d_in, const int* in_sizes, int n_in,
                              void* d_out, int out_size, void* d_ws, size_t ws_size,
                              hipStream_t stream)
{
  const float* h_obs     = (const float*)d_in[0];
  const float* pos_obs   = (const float*)d_in[1];
  const float* pos_query = (const float*)d_in[2];
  const float* fw1       = (const float*)d_in[3];
  const float* fb1       = (const float*)d_in[4];
  const float* fw2       = (const float*)d_in[5];
  const float* fb2       = (const float*)d_in[6];
  const float* log_sigma = (const float*)d_in[7];
  const float* kw1       = (const float*)d_in[8];
  const float* kb1       = (const float*)d_in[9];
  const float* kw2       = (const float*)d_in[10];
  const float* kb2       = (const float*)d_in[11];
  const float* ow        = (const float*)d_in[12];
  const float* ob        = (const float*)d_in[13];
  const float* vw        = (const float*)d_in[14];
  const float* vb        = (const float*)d_in[15];

  float* out = (float*)d_out;
  unsigned short* ws = (unsigned short*)d_ws;

  unsigned short* V_bf  = ws;            // 262144 ushort = 512 KB
  unsigned short* AO_bf = ws + 262144;   // 262144 ushort

  prep_kernel<<<512, 1024, 0, stream>>>(h_obs, fw1, fb1, fw2, fb2,
                                        pos_obs, kw1, V_bf, AO_bf);
  attn_fused<<<NB * NQ / 2, 512, 0, stream>>>(V_bf, AO_bf, kw1, kb1, kw2, kb2,
                                              log_sigma, pos_obs, pos_query,
                                              ow, ob, vw, vb, out);
}